// Round 1
// baseline (313.871 us; speedup 1.0000x reference)
//
#include <hip/hip_runtime.h>
#include <stdint.h>

#define NCLS 172
#define IGN 255
#define HW 65536        // 256*256
#define NPIX 262144     // 4*256*256
#define NB 4
#define EPSV 1e-7f

__device__ __forceinline__ float waveReduceSum(float v) {
    #pragma unroll
    for (int off = 32; off > 0; off >>= 1)
        v += __shfl_down(v, off, 64);
    return v;
}

// Pass 1: one thread per pixel. Online softmax over the C axis (stride HW floats,
// coalesced across the wave). Emits per-pixel m and 1/Z to workspace, CE partial
// sums + valid counts (block-reduced), and inter/counts class histograms via LDS.
__global__ __launch_bounds__(256) void seg_pass1(
    const float* __restrict__ pred, const int* __restrict__ tgt,
    float* __restrict__ mArr, float* __restrict__ wArr,
    float* __restrict__ g_ce, unsigned int* __restrict__ g_nvalid,
    float* __restrict__ g_inter, unsigned int* __restrict__ g_counts)
{
    __shared__ float ldsInter[NCLS];
    __shared__ unsigned int ldsCnt[NCLS];
    __shared__ float ldsRed[8];

    const int tid = threadIdx.x;
    for (int i = tid; i < NCLS; i += 256) { ldsInter[i] = 0.0f; ldsCnt[i] = 0u; }
    __syncthreads();

    const int pix = blockIdx.x * 256 + tid;
    const int b  = pix >> 16;
    const int hw = pix & (HW - 1);
    const float* base = pred + ((size_t)b * NCLS) * (size_t)HW + hw;

    const int t = tgt[pix];
    const bool valid = (t != IGN);
    const int st = valid ? t : 0;

    float m = -3.0e38f, s = 0.0f, xt = 0.0f;
    #pragma unroll 4
    for (int c = 0; c < NCLS; ++c) {
        float x = base[(size_t)c * HW];
        float nm = fmaxf(m, x);
        s = s * __expf(m - nm) + __expf(x - nm);
        m = nm;
        if (c == st) xt = x;
    }
    const float invs = 1.0f / s;
    mArr[pix] = m;
    wArr[pix] = invs;

    const float nll = (m + __logf(s)) - xt;
    const float pt  = __expf(xt - m) * invs;

    float ceP = valid ? nll : 0.0f;
    float nvP = valid ? 1.0f : 0.0f;
    if (valid) {
        atomicAdd(&ldsInter[st], pt);
        atomicAdd(&ldsCnt[st], 1u);
    }

    // block reduce CE partial + valid count
    float vr = waveReduceSum(ceP);
    float nr = waveReduceSum(nvP);
    const int wave = tid >> 6, lane = tid & 63;
    if (lane == 0) { ldsRed[wave] = vr; ldsRed[4 + wave] = nr; }
    __syncthreads();   // also orders the LDS histogram atomics before the flush
    if (tid == 0) {
        float cs = ldsRed[0] + ldsRed[1] + ldsRed[2] + ldsRed[3];
        float ns = ldsRed[4] + ldsRed[5] + ldsRed[6] + ldsRed[7];
        atomicAdd(g_ce, cs);
        atomicAdd(g_nvalid, (unsigned int)(ns + 0.5f));
    }
    for (int i = tid; i < NCLS; i += 256) {
        float vi = ldsInter[i];
        if (vi != 0.0f) atomicAdd(&g_inter[i], vi);
        unsigned int ci = ldsCnt[i];
        if (ci != 0u) atomicAdd(&g_counts[i], ci);
    }
}

// Pass 2: one block per (b,c) plane (688 blocks). union_p[c] += sum over plane
// of exp(x - m_pix) * invZ_pix. pred re-read should hit Infinity Cache; m/w
// arrays (2 MB) stay hot in L2 across the 172 reuses.
__global__ __launch_bounds__(256) void seg_pass2(
    const float* __restrict__ pred, const float* __restrict__ mArr,
    const float* __restrict__ wArr, float* __restrict__ g_union)
{
    const int plane = blockIdx.x;        // b*NCLS + c
    const int c = plane % NCLS;
    const int b = plane / NCLS;
    const float* x  = pred + (size_t)plane * HW;
    const float* mp = mArr + (size_t)b * HW;
    const float* wp = wArr + (size_t)b * HW;

    const int tid = threadIdx.x;
    float acc = 0.0f;
    #pragma unroll 4
    for (int i = tid; i < HW; i += 256)
        acc += __expf(x[i] - mp[i]) * wp[i];

    __shared__ float red[4];
    float v = waveReduceSum(acc);
    const int wave = tid >> 6, lane = tid & 63;
    if (lane == 0) red[wave] = v;
    __syncthreads();
    if (tid == 0) atomicAdd(&g_union[c], red[0] + red[1] + red[2] + red[3]);
}

__global__ __launch_bounds__(256) void seg_finalize(
    const float* __restrict__ g_ce, const unsigned int* __restrict__ g_nvalid,
    const float* __restrict__ g_inter, const float* __restrict__ g_union,
    const unsigned int* __restrict__ g_counts, float* __restrict__ out)
{
    __shared__ float sTerm[256];
    __shared__ float sN[256];
    const int tid = threadIdx.x;
    float term = 0.0f, nv = 0.0f;
    if (tid < NCLS) {
        float u = g_union[tid] + (float)g_counts[tid];
        if (u > 0.0f) {
            term = (2.0f * g_inter[tid] + EPSV) / (u + EPSV);
            nv = 1.0f;
        }
    }
    sTerm[tid] = term; sN[tid] = nv;
    __syncthreads();
    #pragma unroll
    for (int s = 128; s > 0; s >>= 1) {
        if (tid < s) { sTerm[tid] += sTerm[tid + s]; sN[tid] += sN[tid + s]; }
        __syncthreads();
    }
    if (tid == 0) {
        unsigned int nvalid = *g_nvalid;
        float ce = *g_ce / (float)(nvalid > 1u ? nvalid : 1u);
        float nvc = sN[0];
        float dice = (nvc > 0.0f) ? (1.0f - sTerm[0] / fmaxf(nvc, 1.0f)) : 0.0f;
        out[0] = ce + 0.5f * dice;
    }
}

extern "C" void kernel_launch(void* const* d_in, const int* in_sizes, int n_in,
                              void* d_out, int out_size, void* d_ws, size_t ws_size,
                              hipStream_t stream) {
    const float* pred = (const float*)d_in[0];
    const int*   tgt  = (const int*)d_in[1];
    float* out = (float*)d_out;

    char* ws = (char*)d_ws;
    // accumulator region (zeroed each launch): [0,4096)
    float*        g_ce     = (float*)(ws + 0);
    unsigned int* g_nvalid = (unsigned int*)(ws + 4);
    float*        g_inter  = (float*)(ws + 8);
    float*        g_union  = (float*)(ws + 8 + NCLS * 4);
    unsigned int* g_counts = (unsigned int*)(ws + 8 + 2 * NCLS * 4);
    // per-pixel arrays
    float* mArr = (float*)(ws + 4096);
    float* wArr = (float*)(ws + 4096 + (size_t)NPIX * 4);

    hipMemsetAsync(d_ws, 0, 4096, stream);
    seg_pass1<<<NPIX / 256, 256, 0, stream>>>(pred, tgt, mArr, wArr,
                                              g_ce, g_nvalid, g_inter, g_counts);
    seg_pass2<<<NB * NCLS, 256, 0, stream>>>(pred, mArr, wArr, g_union);
    seg_finalize<<<1, 256, 0, stream>>>(g_ce, g_nvalid, g_inter, g_union, g_counts, out);
}